// Round 6
// baseline (282.464 us; speedup 1.0000x reference)
//
#include <hip/hip_runtime.h>
#include <hip/hip_bf16.h>
#include <stdint.h>

typedef _Float16 f16;
typedef _Float16 f16x8 __attribute__((ext_vector_type(8)));
typedef float f32x16 __attribute__((ext_vector_type(16)));
typedef float f32x4 __attribute__((ext_vector_type(4)));
typedef uint32_t u32x4 __attribute__((ext_vector_type(4)));
typedef uint32_t u32x2 __attribute__((ext_vector_type(2)));

#define MFMA(A, B, C) __builtin_amdgcn_mfma_f32_32x32x16_f16((A), (B), (C), 0, 0, 0)

// ---------------------------------------------------------------------------
// Kernel 1: x NCHW f32 [32,256,64,64] -> xt2 f16, MFMA-native layout.
// (unchanged, correctness-proven)
// ---------------------------------------------------------------------------
__global__ __launch_bounds__(256) void nchw_to_nhwc_f16(
    const float* __restrict__ x, f16* __restrict__ xt) {
  __shared__ __align__(16) uint32_t tile[64 * 128];  // 32768 B
  const int bh = blockIdx.x;  // b*64 + h
  const int t = threadIdx.x;
  const float* src = x + (size_t)(bh >> 6) * (256 * 4096) + (bh & 63) * 64;

  const int w4 = t & 15;            // float4 index along w
  const int cq = t >> 4;            // c-quad 0..15
  const int xorv = 4 * (w4 & 7);    // = 4*((w>>2)&7) since w = w4*4+jw
#pragma unroll
  for (int it = 0; it < 4; ++it) {
    const int c0 = it * 64 + cq * 4;
    float4 v0 = *(const float4*)(src + (size_t)(c0 + 0) * 4096 + w4 * 4);
    float4 v1 = *(const float4*)(src + (size_t)(c0 + 1) * 4096 + w4 * 4);
    float4 v2 = *(const float4*)(src + (size_t)(c0 + 2) * 4096 + w4 * 4);
    float4 v3 = *(const float4*)(src + (size_t)(c0 + 3) * 4096 + w4 * 4);
    const float* p0 = (const float*)&v0;
    const float* p1 = (const float*)&v1;
    const float* p2 = (const float*)&v2;
    const float* p3 = (const float*)&v3;
    const int u = it * 32 + cq * 2;  // even word index (c-pair)
#pragma unroll
    for (int jw = 0; jw < 4; ++jw) {
      f16 h0 = (f16)p0[jw], h1 = (f16)p1[jw], h2 = (f16)p2[jw], h3 = (f16)p3[jw];
      uint32_t lo = (uint32_t)__builtin_bit_cast(uint16_t, h0) |
                    ((uint32_t)__builtin_bit_cast(uint16_t, h1) << 16);
      uint32_t hi = (uint32_t)__builtin_bit_cast(uint16_t, h2) |
                    ((uint32_t)__builtin_bit_cast(uint16_t, h3) << 16);
      u32x2 pk = {lo, hi};
      const int w = w4 * 4 + jw;
      *(u32x2*)&tile[w * 128 + (u ^ xorv)] = pk;
    }
  }
  __syncthreads();
  f16* dstb = xt + (size_t)bh * 16384;
#pragma unroll
  for (int it = 0; it < 8; ++it) {
    const int n = it * 256 + t;       // local 16B-unit index, 0..2047
    const int w2 = n & 31;
    const int par = (n >> 5) & 1;
    const int g8 = n >> 6;            // c-octet 0..31
    const int w = par + 2 * w2;
    const u32x4 v = *(const u32x4*)&tile[w * 128 + ((g8 * 4) ^ (4 * ((w >> 2) & 7)))];
    *(u32x4*)(dstb + n * 8) = v;
  }
}

// ---------------------------------------------------------------------------
// Kernel 2: W [32co][256ci][9][9] f32 -> wt2 f16. (unchanged)
// ---------------------------------------------------------------------------
__global__ __launch_bounds__(256) void pack_w(const float* __restrict__ W,
                                              f16* __restrict__ wt) {
  __shared__ float lds[10368];  // [128 ci][81 kk]
  const int t = threadIdx.x;
  const int co = blockIdx.x >> 1;
  const int cih = blockIdx.x & 1;
  const float* src = W + (size_t)(co * 256 + cih * 128) * 81;
  for (int i = t; i < 10368; i += 256) lds[i] = src[i];
  __syncthreads();
  for (int j = t; j < 1296; j += 256) {
    const int kk = j >> 4;
    const int t16 = j & 15;
    const int cicl = t16 >> 2;       // cic within half, 0..3
    const int sg = t16 & 3;          // s*2 + hh
    const int cin = ((sg >> 1) & 1) * 16 + (sg & 1) * 8;  // ci offset in 32
    f16 tmp[8];
#pragma unroll
    for (int e = 0; e < 8; ++e)
      tmp[e] = (f16)lds[(cicl * 32 + cin + e) * 81 + kk];
    const int cic = cih * 4 + cicl;
    *(f16x8*)&wt[(size_t)(((kk * 8 + cic) * 4 + sg) * 32 + co) * 8] = *(f16x8*)tmp;
  }
}

// ---------------------------------------------------------------------------
// Kernel 3: direct conv — r6: 2 oh-pairs per wave (B ds_read amortized x2).
// r5 post-mortem (corrected cycle model): LDS port was the pole — 16 waves x
// 36 x 1KB ds_read_b128 = 576KB/slab/CU = ~6.9k cyc vs MFMA 4.9k. Every
// MFMA ate a private 1KB B read. Fix: each wave owns TWO oh-pairs (4 accs);
// per kw the 4 B ds_reads are shared by both pairs -> 8 MFMAs. LDS bytes
// 1.0 -> 0.5 KB/MFMA: 288KB/slab/CU = 3.4k cyc < MFMA 4.9k. A-VMEM also
// 0.5KB/MFMA (~60B/cyc, at L1 capacity; 64KB/CU row footprint may spill
// reuse to L2 — accepted residual risk).
// Geometry: 256-thr blocks (4 waves x 2 pairs = 8 pairs), grid 512 =
// 2 blocks/CU (LDS 2x73.7KB=147 <=160), 2 waves/SIMD, VGPR ~130.
// Everything else = r3/r5 proven: 4-slot LDS B ring (18KB/slab,
// global_load_lds w=16), ONE barrier/slab, T0=stage[j], T1=stage[j-2],
// rolling depth-1 A prefetch, direct stores, 8 convp partials.
// ---------------------------------------------------------------------------
__global__ __launch_bounds__(256, 2) void conv_direct(
    const f16* __restrict__ xt, const f16* __restrict__ wt,
    float* __restrict__ convp) {
  __shared__ __align__(16) char stg[4 * 18432];  // 73728 B ring
  const int tid = threadIdx.x;
  const int lane = tid & 63;
  const int wave = tid >> 6;           // 0..3
  const int m = lane & 31;
  const int hh = lane >> 5;

  const int blk = blockIdx.x;          // 512 total = 2 per CU
  const int xcd = blk & 7;
  const int r = blk >> 3;              // 0..63
  const int i4 = r >> 4;               // 0..3
  const int rr = r & 15;
  const int og = rr >> 3;              // 0..1
  const int cic = rr & 7;              // 0..7 (this block's 32-ci chunk)
  const int bimg = xcd * 4 + i4;       // image on one XCD (L2 affinity)

  // Two oh-pairs per wave. Pair A: ohp 0..11 (always active).
  // Pair B: ohpA+4 = 4..15; 14,15 (og=1, wave 2,3) are padding.
  const int ohpA = og * 8 + wave;
  const int ohpB = ohpA + 4;
  const bool actB = (ohpB < 14);
  const int ohpBc = actB ? ohpB : ohpA;  // clamp: harmless dup loads

  const char* xb = (const char*)xt;
  const char* wb = (const char*)wt;

  // A lane base for pair p, slab j=0: (bimg*64 + 4*ohp)*32768 + cic*4096
  //                                   + hh*1024 + m*16 ; per slab += 32768.
  const char* ab0 = xb + ((size_t)(bimg * 64 + 4 * ohpA) * 32768 +
                          cic * 4096 + hh * 1024 + m * 16);
  const char* ab1 = xb + ((size_t)(bimg * 64 + 4 * ohpBc) * 32768 +
                          cic * 4096 + hh * 1024 + m * 16);
  const size_t cic2048 = (size_t)cic * 2048;
  const int fragoff = hh * 512 + m * 16;  // in-chunk LDS read offset

#define GLDS(G, L)                                                            \
  __builtin_amdgcn_global_load_lds(                                           \
      (const __attribute__((address_space(1))) void*)(G),                     \
      (__attribute__((address_space(3))) void*)(L), 16, 0, 0)

#define ALOAD(AB, KW, P) \
  (*(const f16x8*)((AB) + (P) * 2048 + ((KW) & 1) * 512 + ((KW) >> 1) * 16))
#define LDSF(P) (*(const f16x8*)(P))

  // Stage slab JN's 9 kk-chunks (18432B) into ring slot JN&3 (r3-proven).
#define STAGE(JN)                                                             \
  {                                                                           \
    const int kkb = (JN) * 9;                                                 \
    char* db = stg + ((JN) & 3) * 18432;                                      \
    _Pragma("unroll") for (int i = 0; i < 4; ++i) {                           \
      const int u = tid + 256 * i;                                            \
      GLDS(wb + (size_t)(kkb + (u >> 7)) * 16384 + cic2048 + (u & 127) * 16,  \
           db + u * 16);                                                      \
    }                                                                         \
    if (tid < 128) {                                                          \
      GLDS(wb + (size_t)(kkb + 8) * 16384 + cic2048 + tid * 16,               \
           db + 16384 + tid * 16);                                            \
    }                                                                         \
  }

  f32x16 accA0, accA1, accB0, accB1;  // [pair][tile]
#pragma unroll
  for (int i = 0; i < 16; ++i) {
    accA0[i] = 0.f; accA1[i] = 0.f; accB0[i] = 0.f; accB1[i] = 0.f;
  }

  STAGE(0)  // prologue: stage slab 0 (latency paid once)

  for (int j = 0; j < 11; ++j) {
    __syncthreads();            // stage[j] ready; prior slab's LDS reads done
    if (j < 8) STAGE(j + 1)     // fill next slot under this slab's compute
    const char* s0 = stg + (j & 3) * 18432 + fragoff;        // T0: kh=j
    const char* s1 = stg + ((j + 2) & 3) * 18432 + fragoff;  // T1: kh=j-2
    // Rolling depth-1 A prefetch for both pairs.
    f16x8 a00 = ALOAD(ab0, 0, 0), a01 = ALOAD(ab0, 0, 1);
    f16x8 a10 = ALOAD(ab1, 0, 0), a11 = ALOAD(ab1, 0, 1);
    if (j >= 2 && j <= 8) {      // both tiles
#pragma unroll
      for (int kw = 0; kw < 9; ++kw) {
        f16x8 n00, n01, n10, n11;
        if (kw < 8) {
          n00 = ALOAD(ab0, kw + 1, 0); n01 = ALOAD(ab0, kw + 1, 1);
          n10 = ALOAD(ab1, kw + 1, 0); n11 = ALOAD(ab1, kw + 1, 1);
        }
        const f16x8 b00 = LDSF(s0 + kw * 2048);
        const f16x8 b01 = LDSF(s0 + kw * 2048 + 1024);
        const f16x8 b10 = LDSF(s1 + kw * 2048);
        const f16x8 b11 = LDSF(s1 + kw * 2048 + 1024);
        accA0 = MFMA(a00, b00, accA0); accA0 = MFMA(a01, b01, accA0);
        accB0 = MFMA(a10, b00, accB0); accB0 = MFMA(a11, b01, accB0);
        accA1 = MFMA(a00, b10, accA1); accA1 = MFMA(a01, b11, accA1);
        accB1 = MFMA(a10, b10, accB1); accB1 = MFMA(a11, b11, accB1);
        a00 = n00; a01 = n01; a10 = n10; a11 = n11;
      }
    } else if (j < 2) {          // T0 only
#pragma unroll
      for (int kw = 0; kw < 9; ++kw) {
        f16x8 n00, n01, n10, n11;
        if (kw < 8) {
          n00 = ALOAD(ab0, kw + 1, 0); n01 = ALOAD(ab0, kw + 1, 1);
          n10 = ALOAD(ab1, kw + 1, 0); n11 = ALOAD(ab1, kw + 1, 1);
        }
        const f16x8 b00 = LDSF(s0 + kw * 2048);
        const f16x8 b01 = LDSF(s0 + kw * 2048 + 1024);
        accA0 = MFMA(a00, b00, accA0); accA0 = MFMA(a01, b01, accA0);
        accB0 = MFMA(a10, b00, accB0); accB0 = MFMA(a11, b01, accB0);
        a00 = n00; a01 = n01; a10 = n10; a11 = n11;
      }
    } else {                     // j > 8: T1 only
#pragma unroll
      for (int kw = 0; kw < 9; ++kw) {
        f16x8 n00, n01, n10, n11;
        if (kw < 8) {
          n00 = ALOAD(ab0, kw + 1, 0); n01 = ALOAD(ab0, kw + 1, 1);
          n10 = ALOAD(ab1, kw + 1, 0); n11 = ALOAD(ab1, kw + 1, 1);
        }
        const f16x8 b10 = LDSF(s1 + kw * 2048);
        const f16x8 b11 = LDSF(s1 + kw * 2048 + 1024);
        accA1 = MFMA(a00, b10, accA1); accA1 = MFMA(a01, b11, accA1);
        accB1 = MFMA(a10, b10, accB1); accB1 = MFMA(a11, b11, accB1);
        a00 = n00; a01 = n01; a10 = n10; a11 = n11;
      }
    }
    ab0 += 32768;
    ab1 += 32768;
  }
#undef STAGE
#undef ALOAD
#undef LDSF
#undef GLDS

  // Direct store: acc reg r, lane (m,hh) holds D[ow=(r&3)+8*(r>>2)+4*hh][co=m].
#define STORE_PAIR(PP, ACT, A0, A1)                                           \
  if (ACT) {                                                                  \
    _Pragma("unroll") for (int tile = 0; tile < 2; ++tile) {                  \
      const int oh = 2 * (PP) + tile;                                         \
      float* cp = convp + (size_t)cic * 802816 +                              \
                  ((size_t)bimg * 784 + oh * 28) * 32 + m;                    \
      const f32x16& a = tile ? (A1) : (A0);                                   \
      _Pragma("unroll") for (int rI = 0; rI < 16; ++rI) {                     \
        const int ow = (rI & 3) + 8 * (rI >> 2) + 4 * hh;                     \
        if (ow < 28) cp[ow * 32] = a[rI];                                     \
      }                                                                       \
    }                                                                         \
  }
  STORE_PAIR(ohpA, true, accA0, accA1)
  STORE_PAIR(ohpB, actB, accB0, accB1)
#undef STORE_PAIR
}

// ---------------------------------------------------------------------------
// Kernel 4: epilogue. v = sum(8 partials)+bias; sq=8v^2;
// scale = sq/((1+sq)*sqrt(sq+1e-8)); y=v*scale broadcast to 8 t-slots.
// (unchanged)
// ---------------------------------------------------------------------------
__global__ __launch_bounds__(256) void epilogue(const float* __restrict__ convp,
                                                const float* __restrict__ bias,
                                                float* __restrict__ out) {
  const int gi = blockIdx.x * 256 + threadIdx.x;  // 100352 total, exact grid
  const int base = gi * 8;
  const int p = gi >> 2;
  const int co0 = (gi & 3) * 8;
  const int bi = p / 784;
  const int pix = p - bi * 784;
  f32x4 v0 = {0.f, 0.f, 0.f, 0.f}, v1 = {0.f, 0.f, 0.f, 0.f};
#pragma unroll
  for (int qq = 0; qq < 8; ++qq) {
    v0 += *(const f32x4*)&convp[(size_t)qq * 802816 + base];
    v1 += *(const f32x4*)&convp[(size_t)qq * 802816 + base + 4];
  }
  float vb[8];
#pragma unroll
  for (int jj = 0; jj < 4; ++jj) {
    vb[jj] = v0[jj] + bias[co0 + jj];
    vb[4 + jj] = v1[jj] + bias[co0 + 4 + jj];
  }
  float* ob = out + (size_t)bi * 200704 + pix * 8;
#pragma unroll
  for (int jj = 0; jj < 8; ++jj) {
    const float vv = vb[jj];
    const float sq = 8.f * vv * vv;
    const float scale = sq / ((1.f + sq) * sqrtf(sq + 1e-8f));
    const float y = vv * scale;
    const f32x4 qv = {y, y, y, y};
    float* o = ob + (size_t)(co0 + jj) * 6272;
    *(f32x4*)o = qv;
    *(f32x4*)(o + 4) = qv;
  }
}

// ---------------------------------------------------------------------------
extern "C" void kernel_launch(void* const* d_in, const int* in_sizes, int n_in,
                              void* d_out, int out_size, void* d_ws,
                              size_t ws_size, hipStream_t stream) {
  const float* x = (const float*)d_in[0];     // [32,256,64,64]
  const float* W = (const float*)d_in[1];     // [32,256,9,9]
  const float* bias = (const float*)d_in[2];  // [32]
  float* out = (float*)d_out;                 // 6422528 f32

  char* ws = (char*)d_ws;
  f16* xt = (f16*)ws;                                // 67,108,864 B
  f16* wt = (f16*)(ws + 67108864);                   //  1,327,104 B
  float* convp = (float*)(ws + 67108864 + 1327104);  // 25,690,112 B (8 parts)

  nchw_to_nhwc_f16<<<dim3(2048), dim3(256), 0, stream>>>(x, xt);
  pack_w<<<dim3(64), dim3(256), 0, stream>>>(W, wt);
  conv_direct<<<dim3(512), dim3(256), 0, stream>>>(xt, wt, convp);
  epilogue<<<dim3(392), dim3(256), 0, stream>>>(convp, bias, out);
}

// Round 8
// 281.886 us; speedup vs baseline: 1.0021x; 1.0021x over previous
//
#include <hip/hip_runtime.h>
#include <hip/hip_bf16.h>
#include <stdint.h>

typedef _Float16 f16;
typedef _Float16 f16x8 __attribute__((ext_vector_type(8)));
typedef float f32x16 __attribute__((ext_vector_type(16)));
typedef float f32x4 __attribute__((ext_vector_type(4)));
typedef uint32_t u32x4 __attribute__((ext_vector_type(4)));
typedef uint32_t u32x2 __attribute__((ext_vector_type(2)));

#define MFMA(A, B, C) __builtin_amdgcn_mfma_f32_32x32x16_f16((A), (B), (C), 0, 0, 0)

// ---------------------------------------------------------------------------
// Kernel 1: x NCHW f32 [32,256,64,64] -> xt2 f16, MFMA-native layout.
// (unchanged, correctness-proven)
// ---------------------------------------------------------------------------
__global__ __launch_bounds__(256) void nchw_to_nhwc_f16(
    const float* __restrict__ x, f16* __restrict__ xt) {
  __shared__ __align__(16) uint32_t tile[64 * 128];  // 32768 B
  const int bh = blockIdx.x;  // b*64 + h
  const int t = threadIdx.x;
  const float* src = x + (size_t)(bh >> 6) * (256 * 4096) + (bh & 63) * 64;

  const int w4 = t & 15;            // float4 index along w
  const int cq = t >> 4;            // c-quad 0..15
  const int xorv = 4 * (w4 & 7);    // = 4*((w>>2)&7) since w = w4*4+jw
#pragma unroll
  for (int it = 0; it < 4; ++it) {
    const int c0 = it * 64 + cq * 4;
    float4 v0 = *(const float4*)(src + (size_t)(c0 + 0) * 4096 + w4 * 4);
    float4 v1 = *(const float4*)(src + (size_t)(c0 + 1) * 4096 + w4 * 4);
    float4 v2 = *(const float4*)(src + (size_t)(c0 + 2) * 4096 + w4 * 4);
    float4 v3 = *(const float4*)(src + (size_t)(c0 + 3) * 4096 + w4 * 4);
    const float* p0 = (const float*)&v0;
    const float* p1 = (const float*)&v1;
    const float* p2 = (const float*)&v2;
    const float* p3 = (const float*)&v3;
    const int u = it * 32 + cq * 2;  // even word index (c-pair)
#pragma unroll
    for (int jw = 0; jw < 4; ++jw) {
      f16 h0 = (f16)p0[jw], h1 = (f16)p1[jw], h2 = (f16)p2[jw], h3 = (f16)p3[jw];
      uint32_t lo = (uint32_t)__builtin_bit_cast(uint16_t, h0) |
                    ((uint32_t)__builtin_bit_cast(uint16_t, h1) << 16);
      uint32_t hi = (uint32_t)__builtin_bit_cast(uint16_t, h2) |
                    ((uint32_t)__builtin_bit_cast(uint16_t, h3) << 16);
      u32x2 pk = {lo, hi};
      const int w = w4 * 4 + jw;
      *(u32x2*)&tile[w * 128 + (u ^ xorv)] = pk;
    }
  }
  __syncthreads();
  f16* dstb = xt + (size_t)bh * 16384;
#pragma unroll
  for (int it = 0; it < 8; ++it) {
    const int n = it * 256 + t;       // local 16B-unit index, 0..2047
    const int w2 = n & 31;
    const int par = (n >> 5) & 1;
    const int g8 = n >> 6;            // c-octet 0..31
    const int w = par + 2 * w2;
    const u32x4 v = *(const u32x4*)&tile[w * 128 + ((g8 * 4) ^ (4 * ((w >> 2) & 7)))];
    *(u32x4*)(dstb + n * 8) = v;
  }
}

// ---------------------------------------------------------------------------
// Kernel 2: W [32co][256ci][9][9] f32 -> wt2 f16. (unchanged)
// ---------------------------------------------------------------------------
__global__ __launch_bounds__(256) void pack_w(const float* __restrict__ W,
                                              f16* __restrict__ wt) {
  __shared__ float lds[10368];  // [128 ci][81 kk]
  const int t = threadIdx.x;
  const int co = blockIdx.x >> 1;
  const int cih = blockIdx.x & 1;
  const float* src = W + (size_t)(co * 256 + cih * 128) * 81;
  for (int i = t; i < 10368; i += 256) lds[i] = src[i];
  __syncthreads();
  for (int j = t; j < 1296; j += 256) {
    const int kk = j >> 4;
    const int t16 = j & 15;
    const int cicl = t16 >> 2;       // cic within half, 0..3
    const int sg = t16 & 3;          // s*2 + hh
    const int cin = ((sg >> 1) & 1) * 16 + (sg & 1) * 8;  // ci offset in 32
    f16 tmp[8];
#pragma unroll
    for (int e = 0; e < 8; ++e)
      tmp[e] = (f16)lds[(cicl * 32 + cin + e) * 81 + kk];
    const int cic = cih * 4 + cicl;
    *(f16x8*)&wt[(size_t)(((kk * 8 + cic) * 4 + sg) * 32 + co) * 8] = *(f16x8*)tmp;
  }
}

// ---------------------------------------------------------------------------
// Kernel 3: direct conv — r7: 16-ci K-chunks = r6 ratios + r5 occupancy.
// r5 (4 waves/SIMD, 1KB/MFMA) = best; r6 (2 waves/SIMD, 0.5KB/MFMA)
// regressed. r7 gets BOTH: split K into 16 chunks of 16 ci (one MFMA's K).
//  * Block = 8 waves x 2 pairs = all 16 oh-pairs of one (img,k16) column.
//    Grid 512 = 32 img x 16 k16 -> 2 blocks/CU -> 16 waves/CU = 4/SIMD.
//  * Per kw per wave: 2 A loads + 2 B ds_reads -> 4 MFMAs (2 pairs x T0/T1)
//    = 0.5 KB/MFMA on both LDS and A-VMEM. Poles per CU per slab:
//    MFMA ~4.6-5.3k cyc (bound), LDS ~2.9k, A ~2.5-5k (L1-partial).
//  * B ring slot = 9KB (9 kk x 1KB); 4-slot ring = 36.9KB; 2 blk = 73.7KB.
//  * VGPR ~106 < 128 -> __launch_bounds__(512,4) holds 2 blocks/CU.
//  * A/B addressing = proven baseline formulas with the 16-ci half (sp)
//    folded into the base (pure base-fold, no layout change).
//  * Cost: convp 16 partials (51MB), epilogue sums 16. Accepted.
// ---------------------------------------------------------------------------
__global__ __launch_bounds__(512, 4) void conv_direct(
    const f16* __restrict__ xt, const f16* __restrict__ wt,
    float* __restrict__ convp) {
  __shared__ __align__(16) char stg[4 * 9216];  // 36864 B ring
  const int tid = threadIdx.x;
  const int lane = tid & 63;
  const int wave = tid >> 6;           // 0..7
  const int m = lane & 31;
  const int hh = lane >> 5;

  const int blk = blockIdx.x;          // 512 total = 2 per CU
  const int xcd = blk & 7;
  const int r = blk >> 3;              // 0..63
  const int k16 = r >> 2;              // 0..15 (16-ci K chunk)
  const int i4 = r & 3;
  const int bimg = xcd * 4 + i4;       // image on one XCD (L2 affinity)
  const int cic = k16 >> 1;            // 32-ci chunk
  const int sp = k16 & 1;              // which 16-ci half (p == s)

  // Two oh-pairs per wave: pair A = wave (0..7, always active),
  // pair B = wave+8 (8..15; 14,15 are padding).
  const int ohpA = wave;
  const int ohpB = wave + 8;
  const bool actB = (ohpB < 14);
  const int ohpBc = actB ? ohpB : ohpA;  // clamp: harmless dup loads

  const char* xb = (const char*)xt;
  const char* wb = (const char*)wt;

  // A lane base (pair p, slab j=0): (bimg*64 + 4*ohp)*32768 + cic*4096
  //   + sp*2048 + hh*1024 + m*16 ; per slab += 32768.
  // In-slab: (kw&1)*512 + (kw>>1)*16  (baseline-proven window slide).
  const char* ab0 = xb + ((size_t)(bimg * 64 + 4 * ohpA) * 32768 +
                          cic * 4096 + sp * 2048 + hh * 1024 + m * 16);
  const char* ab1 = xb + ((size_t)(bimg * 64 + 4 * ohpBc) * 32768 +
                          cic * 4096 + sp * 2048 + hh * 1024 + m * 16);
  const size_t soff = (size_t)cic * 2048 + sp * 1024;  // B slice offset
  const int fragoff = hh * 512 + m * 16;  // in-frag LDS read offset

#define GLDS(G, L)                                                            \
  __builtin_amdgcn_global_load_lds(                                           \
      (const __attribute__((address_space(1))) void*)(G),                     \
      (__attribute__((address_space(3))) void*)(L), 16, 0, 0)

#define ALOAD(AB, KW) \
  (*(const f16x8*)((AB) + ((KW) & 1) * 512 + ((KW) >> 1) * 16))
#define LDSF(P) (*(const f16x8*)(P))

  // Stage slab JN's 9 kk-frags (9 x 1KB) into ring slot JN&3.
  // kk frag u (u=0..63) -> db + kk*1024 + u*16 (lane-linear, HW req).
#define STAGE(JN)                                                             \
  {                                                                           \
    const int kkb = (JN) * 9;                                                 \
    char* db = stg + ((JN) & 3) * 9216;                                       \
    GLDS(wb + (size_t)(kkb + (tid >> 6)) * 16384 + soff + (tid & 63) * 16,    \
         db + tid * 16);                                                      \
    if (tid < 64) {                                                           \
      GLDS(wb + (size_t)(kkb + 8) * 16384 + soff + tid * 16,                  \
           db + 8192 + tid * 16);                                             \
    }                                                                         \
  }

  f32x16 accA0, accA1, accB0, accB1;  // [pair][tile]
#pragma unroll
  for (int i = 0; i < 16; ++i) {
    accA0[i] = 0.f; accA1[i] = 0.f; accB0[i] = 0.f; accB1[i] = 0.f;
  }

  STAGE(0)  // prologue: stage slab 0 (latency paid once)

  for (int j = 0; j < 11; ++j) {
    __syncthreads();            // stage[j] ready; prior slab's LDS reads done
    if (j < 8) STAGE(j + 1)     // fill next slot under this slab's compute
    const char* s0 = stg + (j & 3) * 9216 + fragoff;        // T0: kh=j
    const char* s1 = stg + ((j + 2) & 3) * 9216 + fragoff;  // T1: kh=j-2
    // Rolling depth-1 A prefetch for both pairs.
    f16x8 a0 = ALOAD(ab0, 0);
    f16x8 a1 = ALOAD(ab1, 0);
    if (j >= 2 && j <= 8) {      // both tiles
#pragma unroll
      for (int kw = 0; kw < 9; ++kw) {
        f16x8 n0, n1;
        if (kw < 8) { n0 = ALOAD(ab0, kw + 1); n1 = ALOAD(ab1, kw + 1); }
        const f16x8 b0 = LDSF(s0 + kw * 1024);
        const f16x8 b1 = LDSF(s1 + kw * 1024);
        accA0 = MFMA(a0, b0, accA0);
        accB0 = MFMA(a1, b0, accB0);
        accA1 = MFMA(a0, b1, accA1);
        accB1 = MFMA(a1, b1, accB1);
        a0 = n0; a1 = n1;
      }
    } else if (j < 2) {          // T0 only
#pragma unroll
      for (int kw = 0; kw < 9; ++kw) {
        f16x8 n0, n1;
        if (kw < 8) { n0 = ALOAD(ab0, kw + 1); n1 = ALOAD(ab1, kw + 1); }
        const f16x8 b0 = LDSF(s0 + kw * 1024);
        accA0 = MFMA(a0, b0, accA0);
        accB0 = MFMA(a1, b0, accB0);
        a0 = n0; a1 = n1;
      }
    } else {                     // j > 8: T1 only
#pragma unroll
      for (int kw = 0; kw < 9; ++kw) {
        f16x8 n0, n1;
        if (kw < 8) { n0 = ALOAD(ab0, kw + 1); n1 = ALOAD(ab1, kw + 1); }
        const f16x8 b1 = LDSF(s1 + kw * 1024);
        accA1 = MFMA(a0, b1, accA1);
        accB1 = MFMA(a1, b1, accB1);
        a0 = n0; a1 = n1;
      }
    }
    ab0 += 32768;
    ab1 += 32768;
  }
#undef STAGE
#undef ALOAD
#undef LDSF
#undef GLDS

  // Direct store: acc reg r, lane (m,hh) holds D[ow=(r&3)+8*(r>>2)+4*hh][co=m].
#define STORE_PAIR(PP, ACT, A0, A1)                                           \
  if (ACT) {                                                                  \
    _Pragma("unroll") for (int tile = 0; tile < 2; ++tile) {                  \
      const int oh = 2 * (PP) + tile;                                         \
      float* cp = convp + (size_t)k16 * 802816 +                              \
                  ((size_t)bimg * 784 + oh * 28) * 32 + m;                    \
      const f32x16& a = tile ? (A1) : (A0);                                   \
      _Pragma("unroll") for (int rI = 0; rI < 16; ++rI) {                     \
        const int ow = (rI & 3) + 8 * (rI >> 2) + 4 * hh;                     \
        if (ow < 28) cp[ow * 32] = a[rI];                                     \
      }                                                                       \
    }                                                                         \
  }
  STORE_PAIR(ohpA, true, accA0, accA1)
  STORE_PAIR(ohpB, actB, accB0, accB1)
#undef STORE_PAIR
}

// ---------------------------------------------------------------------------
// Kernel 4: epilogue. v = sum(16 partials)+bias; sq=8v^2;
// scale = sq/((1+sq)*sqrt(sq+1e-8)); y=v*scale broadcast to 8 t-slots.
// ---------------------------------------------------------------------------
__global__ __launch_bounds__(256) void epilogue(const float* __restrict__ convp,
                                                const float* __restrict__ bias,
                                                float* __restrict__ out) {
  const int gi = blockIdx.x * 256 + threadIdx.x;  // 100352 total, exact grid
  const int base = gi * 8;
  const int p = gi >> 2;
  const int co0 = (gi & 3) * 8;
  const int bi = p / 784;
  const int pix = p - bi * 784;
  f32x4 v0 = {0.f, 0.f, 0.f, 0.f}, v1 = {0.f, 0.f, 0.f, 0.f};
#pragma unroll
  for (int qq = 0; qq < 16; ++qq) {
    v0 += *(const f32x4*)&convp[(size_t)qq * 802816 + base];
    v1 += *(const f32x4*)&convp[(size_t)qq * 802816 + base + 4];
  }
  float vb[8];
#pragma unroll
  for (int jj = 0; jj < 4; ++jj) {
    vb[jj] = v0[jj] + bias[co0 + jj];
    vb[4 + jj] = v1[jj] + bias[co0 + 4 + jj];
  }
  float* ob = out + (size_t)bi * 200704 + pix * 8;
#pragma unroll
  for (int jj = 0; jj < 8; ++jj) {
    const float vv = vb[jj];
    const float sq = 8.f * vv * vv;
    const float scale = sq / ((1.f + sq) * sqrtf(sq + 1e-8f));
    const float y = vv * scale;
    const f32x4 qv = {y, y, y, y};
    float* o = ob + (size_t)(co0 + jj) * 6272;
    *(f32x4*)o = qv;
    *(f32x4*)(o + 4) = qv;
  }
}

// ---------------------------------------------------------------------------
extern "C" void kernel_launch(void* const* d_in, const int* in_sizes, int n_in,
                              void* d_out, int out_size, void* d_ws,
                              size_t ws_size, hipStream_t stream) {
  const float* x = (const float*)d_in[0];     // [32,256,64,64]
  const float* W = (const float*)d_in[1];     // [32,256,9,9]
  const float* bias = (const float*)d_in[2];  // [32]
  float* out = (float*)d_out;                 // 6422528 f32

  char* ws = (char*)d_ws;
  f16* xt = (f16*)ws;                                // 67,108,864 B
  f16* wt = (f16*)(ws + 67108864);                   //  1,327,104 B
  float* convp = (float*)(ws + 67108864 + 1327104);  // 51,380,224 B (16 parts)

  nchw_to_nhwc_f16<<<dim3(2048), dim3(256), 0, stream>>>(x, xt);
  pack_w<<<dim3(64), dim3(256), 0, stream>>>(W, wt);
  conv_direct<<<dim3(512), dim3(512), 0, stream>>>(xt, wt, convp);
  epilogue<<<dim3(392), dim3(256), 0, stream>>>(convp, bias, out);
}